// Round 6
// baseline (332.863 us; speedup 1.0000x reference)
//
#include <hip/hip_runtime.h>

#define NB     8192
#define HDIM   64
#define SEQ    180
#define MT     16     // batch rows per block
#define SB     68     // bf16 LDS row stride: 34 dwords -> 0 bank conflicts (R4/R5-verified)
#define XSP    100    // xs prologue row stride (floats)
#define OSP    361    // ostage row stride (dwords): 361%32=9 -> duty writes conflict-free

typedef __bf16 bf16x8 __attribute__((ext_vector_type(8)));
typedef float  f32x4  __attribute__((ext_vector_type(4)));

#define L2E 1.44269504088896340736f

__device__ __forceinline__ float tanh_f(float x) {
    float e = __builtin_amdgcn_exp2f((2.0f * L2E) * x);
    return 1.0f - 2.0f * __builtin_amdgcn_rcpf(1.0f + e);
}

#define MFMA __builtin_amdgcn_mfma_f32_16x16x32_bf16

// Fused h0 + 180 GRU steps + per-step output head.
// Block = 256 threads = 4 waves, 16 batch rows, 512 blocks (2 blocks/CU).
// KEY CHANGE vs R3: no global stores inside the time loop. Outputs go to an
// LDS staging buffer; __syncthreads then only drains LDS (lgkmcnt, ~30 cyc)
// instead of waiting for global store acks (vmcnt(0), ~300-1000 cyc) every
// step. One coalesced LDS->global bulk copy in the epilogue.
__global__ __launch_bounds__(256) void gru_all(
        const float* __restrict__ z, const int* __restrict__ labels,
        const float* __restrict__ embed_w, const float* __restrict__ fc_w,
        const float* __restrict__ fc_b, const float* __restrict__ w_hh,
        const float* __restrict__ b_ih, const float* __restrict__ b_hh,
        const float* __restrict__ out_w, const float* __restrict__ out_b,
        float* __restrict__ out) {
    __shared__ __align__(16) __bf16 hbuf[2][2][MT * SB];  // [buf][hi/lo]
    __shared__ __align__(16) float  ostage[MT * OSP];     // [row][step*2+o]
    __shared__ __align__(16) float  xs[MT * XSP];         // h0 input [z|embed]

    const int t = threadIdx.x;
    const int w = t >> 6;          // wave 0..3
    const int l = t & 63;
    const int q = l >> 4;          // quad 0..3
    const int n16 = l & 15;
    const int jg = 16 * w + n16;   // gate column this lane owns
    const int bbase = blockIdx.x * MT;

    // ---- prologue A: stage x = [z, embed(labels)] for 16 rows into LDS ----
    for (int c = t; c < MT * 24; c += 256) {    // 24 f32x4 chunks per row
        int m = c / 24, kk = (c % 24) * 4;
        f32x4 v;
        if (kk < 32) v = *(const f32x4*)(z + (size_t)(bbase + m) * 32 + kk);
        else         v = *(const f32x4*)(embed_w + labels[bbase + m] * 64 + (kk - 32));
        *(f32x4*)(xs + m * XSP + kk) = v;
    }

    // ---- persistent w_hh fragments (hi/lo split), 48 VGPRs ----
    // B-frag for mfma_f32_16x16x32_bf16: B[k = q*8+j][n16]; value w_hh[jg_g][k]
    bf16x8 whi[3][2], wlo[3][2];
#pragma unroll
    for (int g = 0; g < 3; ++g) {
        const float* pr = w_hh + (g * 64 + jg) * HDIM;
#pragma unroll
        for (int ks = 0; ks < 2; ++ks) {
            const float* p = pr + ks * 32 + q * 8;
            f32x4 va = *(const f32x4*)(p);
            f32x4 vb = *(const f32x4*)(p + 4);
#pragma unroll
            for (int j2 = 0; j2 < 4; ++j2) {
                __bf16 hiA = (__bf16)va[j2];
                whi[g][ks][j2] = hiA;
                wlo[g][ks][j2] = (__bf16)(va[j2] - (float)hiA);
                __bf16 hiB = (__bf16)vb[j2];
                whi[g][ks][4 + j2] = hiB;
                wlo[g][ks][4 + j2] = (__bf16)(vb[j2] - (float)hiB);
            }
        }
    }

    // ---- output-head B fragments: B[k][n] = out_w[n][k] for n<2 else 0 ----
    bf16x8 obhi[2], oblo[2];
#pragma unroll
    for (int ks = 0; ks < 2; ++ks) {
        f32x4 va = {0.f, 0.f, 0.f, 0.f}, vb = {0.f, 0.f, 0.f, 0.f};
        if (n16 < 2) {
            va = *(const f32x4*)(out_w + n16 * 64 + ks * 32 + q * 8);
            vb = *(const f32x4*)(out_w + n16 * 64 + ks * 32 + q * 8 + 4);
        }
#pragma unroll
        for (int j2 = 0; j2 < 4; ++j2) {
            __bf16 hiA = (__bf16)va[j2];
            obhi[ks][j2] = hiA;
            oblo[ks][j2] = (__bf16)(va[j2] - (float)hiA);
            __bf16 hiB = (__bf16)vb[j2];
            obhi[ks][4 + j2] = hiB;
            oblo[ks][4 + j2] = (__bf16)(vb[j2] - (float)hiB);
        }
    }
    const float bo = (n16 == 0) ? out_b[0] : (n16 == 1) ? out_b[1] : 0.f;
    const f32x4 obias = {bo, bo, bo, bo};
    const f32x4 kZ = {0.f, 0.f, 0.f, 0.f};

    // per-lane gate constants (biases folded into the exp2 fma)
    const float cR    = -L2E * (b_ih[jg] + b_hh[jg]);
    const float cZ    = -L2E * (b_ih[64 + jg] + b_hh[64 + jg]);
    const float bnacc = b_hh[128 + jg];
    const float cN    = 2.0f * L2E * b_ih[128 + jg];

    const int rdoff = n16 * SB + q * 8;    // A-frag element offset
    const int wroff = (4 * q) * SB + jg;   // state-write element offset
    const int ooff  = (4 * q) * OSP + n16; // ostage base for this lane's rows

    __syncthreads();   // xs ready

    // ---- prologue B: h0 = tanh(fc_b + fc_w . x); each lane -> its 4 rows ----
    float hprev[4];
    {
        float a[4];
#pragma unroll
        for (int r = 0; r < 4; ++r) a[r] = fc_b[jg];
        const float* wr = fc_w + jg * 96;
        for (int kc = 0; kc < 24; ++kc) {
            f32x4 wv = *(const f32x4*)(wr + kc * 4);
#pragma unroll
            for (int r = 0; r < 4; ++r) {
                f32x4 xv = *(const f32x4*)(xs + (4 * q + r) * XSP + kc * 4);
                a[r] += wv[0] * xv[0] + wv[1] * xv[1] + wv[2] * xv[2] + wv[3] * xv[3];
            }
        }
#pragma unroll
        for (int r = 0; r < 4; ++r) {
            float h = tanh_f(a[r]);
            hprev[r] = h;
            __bf16 hb = (__bf16)h;
            hbuf[0][0][wroff + r * SB] = hb;
            hbuf[0][1][wroff + r * SB] = (__bf16)(h - (float)hb);
        }
    }
    __syncthreads();   // state 0 published in buf 0

    for (int u = 0; u < SEQ / 4; ++u) {
#pragma unroll
        for (int s = 0; s < 4; ++s) {
            const int p = s & 1;
            const __bf16* Hh = hbuf[p][0];
            const __bf16* Hl = hbuf[p][1];
            __bf16* Nh = hbuf[1 - p][0];
            __bf16* Nl = hbuf[1 - p][1];

            // A-frags of state i = 4u+s: A[m=n16][k=q*8+j], two k-halves
            bf16x8 ahi0 = *(const bf16x8*)(Hh + rdoff);
            bf16x8 ahi1 = *(const bf16x8*)(Hh + rdoff + 32);
            bf16x8 alo0 = *(const bf16x8*)(Hl + rdoff);
            bf16x8 alo1 = *(const bf16x8*)(Hl + rdoff + 32);

            // output row i-1 (state i) on static duty wave (s+3)&3 -> LDS only
            if ((u | s) != 0 && w == ((s + 3) & 3)) {
                f32x4 o = obias;
                o = MFMA(ahi0, obhi[0], o, 0, 0, 0);
                o = MFMA(ahi1, obhi[1], o, 0, 0, 0);
                o = MFMA(alo0, obhi[0], o, 0, 0, 0);
                o = MFMA(alo1, obhi[1], o, 0, 0, 0);
                o = MFMA(ahi0, oblo[0], o, 0, 0, 0);
                o = MFMA(ahi1, oblo[1], o, 0, 0, 0);
                if (n16 < 2) {
                    const int so = ooff + (4 * u + s - 1) * 2;
#pragma unroll
                    for (int r = 0; r < 4; ++r)
                        ostage[so + r * OSP] = o[r];
                }
            }

            // gates: 6-deep chains (R3-proven ordering)
            f32x4 aR, aZ, aN;
            aR = MFMA(ahi0, whi[0][0], kZ, 0, 0, 0);
            aZ = MFMA(ahi0, whi[1][0], kZ, 0, 0, 0);
            aN = MFMA(ahi0, whi[2][0], kZ, 0, 0, 0);
            aR = MFMA(alo0, whi[0][0], aR, 0, 0, 0);
            aZ = MFMA(alo0, whi[1][0], aZ, 0, 0, 0);
            aN = MFMA(alo0, whi[2][0], aN, 0, 0, 0);
            aR = MFMA(ahi0, wlo[0][0], aR, 0, 0, 0);
            aZ = MFMA(ahi0, wlo[1][0], aZ, 0, 0, 0);
            aN = MFMA(ahi0, wlo[2][0], aN, 0, 0, 0);
            aR = MFMA(ahi1, whi[0][1], aR, 0, 0, 0);
            aZ = MFMA(ahi1, whi[1][1], aZ, 0, 0, 0);
            aN = MFMA(ahi1, whi[2][1], aN, 0, 0, 0);
            aR = MFMA(alo1, whi[0][1], aR, 0, 0, 0);
            aZ = MFMA(alo1, whi[1][1], aZ, 0, 0, 0);
            aN = MFMA(alo1, whi[2][1], aN, 0, 0, 0);
            aR = MFMA(ahi1, wlo[0][1], aR, 0, 0, 0);
            aZ = MFMA(ahi1, wlo[1][1], aZ, 0, 0, 0);
            aN = MFMA(ahi1, wlo[2][1], aN, 0, 0, 0);

#pragma unroll
            for (int r = 0; r < 4; ++r) {
                float eR = __builtin_amdgcn_exp2f(__builtin_fmaf(-L2E, aR[r], cR));
                float rg = __builtin_amdgcn_rcpf(eR + 1.0f);
                float eZ = __builtin_amdgcn_exp2f(__builtin_fmaf(-L2E, aZ[r], cZ));
                float zg = __builtin_amdgcn_rcpf(eZ + 1.0f);
                float m  = aN[r] + bnacc;
                float eN = __builtin_amdgcn_exp2f(__builtin_fmaf(2.0f * L2E, rg * m, cN));
                float d  = __builtin_amdgcn_rcpf(eN + 1.0f);
                float ng = __builtin_fmaf(-2.0f, d, 1.0f);
                float hn = __builtin_fmaf(zg, hprev[r] - ng, ng);
                hprev[r] = hn;
                __bf16 hb = (__bf16)hn;
                Nh[wroff + r * SB] = hb;
                Nl[wroff + r * SB] = (__bf16)(hn - (float)hb);
            }
            __syncthreads();   // state i+1 published (LDS-only drain)
        }
    }

    // final output row 179 (state 180, in buf 0), duty wave 3 -> LDS
    if (w == 3) {
        const __bf16* Hh = hbuf[0][0];
        const __bf16* Hl = hbuf[0][1];
        bf16x8 ahi0 = *(const bf16x8*)(Hh + rdoff);
        bf16x8 ahi1 = *(const bf16x8*)(Hh + rdoff + 32);
        bf16x8 alo0 = *(const bf16x8*)(Hl + rdoff);
        bf16x8 alo1 = *(const bf16x8*)(Hl + rdoff + 32);
        f32x4 o = obias;
        o = MFMA(ahi0, obhi[0], o, 0, 0, 0);
        o = MFMA(ahi1, obhi[1], o, 0, 0, 0);
        o = MFMA(alo0, obhi[0], o, 0, 0, 0);
        o = MFMA(alo1, obhi[1], o, 0, 0, 0);
        o = MFMA(ahi0, oblo[0], o, 0, 0, 0);
        o = MFMA(ahi1, oblo[1], o, 0, 0, 0);
        if (n16 < 2) {
#pragma unroll
            for (int r = 0; r < 4; ++r)
                ostage[ooff + 358 + r * OSP] = o[r];
        }
    }
    __syncthreads();   // all outputs staged

    // ---- epilogue: coalesced bulk copy ostage -> out (contiguous region) ----
    // Block's slice: out[bbase*360 .. +5760), row-major [16][360].
    float* ob = out + (size_t)bbase * (SEQ * 2);
    for (int c = t; c < MT * 90; c += 256) {     // 90 f32x4 chunks per row
        int m = c / 90;
        int o4 = (c - m * 90) * 4;
        f32x4 v = *(const f32x4*)(ostage + m * OSP + o4);
        *(f32x4*)(ob + m * 360 + o4) = v;
    }
}

extern "C" void kernel_launch(void* const* d_in, const int* in_sizes, int n_in,
                              void* d_out, int out_size, void* d_ws, size_t ws_size,
                              hipStream_t stream) {
    (void)in_sizes; (void)n_in; (void)out_size; (void)d_ws; (void)ws_size;
    const float* z       = (const float*)d_in[0];
    const int*   labels  = (const int*)d_in[1];
    const float* embed_w = (const float*)d_in[2];
    const float* fc_w    = (const float*)d_in[3];
    const float* fc_b    = (const float*)d_in[4];
    // d_in[5] = w_ih: unused (GRU input is all zeros; b_ih carries the effect)
    const float* w_hh    = (const float*)d_in[6];
    const float* b_ih    = (const float*)d_in[7];
    const float* b_hh    = (const float*)d_in[8];
    const float* out_w   = (const float*)d_in[9];
    const float* out_b   = (const float*)d_in[10];
    float* out = (float*)d_out;

    gru_all<<<NB / MT, 256, 0, stream>>>(z, labels, embed_w, fc_w, fc_b,
                                         w_hh, b_ih, b_hh, out_w, out_b, out);
}

// Round 7
// 201.082 us; speedup vs baseline: 1.6554x; 1.6554x over previous
//
#include <hip/hip_runtime.h>

#define NB     8192
#define HDIM   64
#define SEQ    180
#define MT     16     // batch rows per block
#define SB     72     // bf16 LDS row stride: 144 B, KEEPS 16B alignment (SB=68 regressed ~100us: misaligned b128)
#define XSP    100    // xs prologue row stride (floats)

typedef __bf16 bf16x8 __attribute__((ext_vector_type(8)));
typedef float  f32x4  __attribute__((ext_vector_type(4)));

#define L2E 1.44269504088896340736f

__device__ __forceinline__ float tanh_f(float x) {
    float e = __builtin_amdgcn_exp2f((2.0f * L2E) * x);
    return 1.0f - 2.0f * __builtin_amdgcn_rcpf(1.0f + e);
}

#define MFMA __builtin_amdgcn_mfma_f32_16x16x32_bf16

// Fused h0 + 180 GRU steps + per-step output head. R3 skeleton (174us proven):
// 4 waves, 16 rows/block, 512 blocks (2/CU), double-buffered LDS h-plane,
// one barrier/step, x4-unrolled time loop, direct global output stores.
// R7 change: h enters MFMA as plain bf16 (hhi plane only; hlo dropped).
// w stays hi/lo-exact. The fp32 carry path h_new = n + z*(hprev-n) uses the
// exact register hprev, so rounding enters only via the W-multiplied branch.
// 12 MFMA/wave-step (was 18), 2 ds_read_b128 (was 4), 4 ds_write_b16 (was 8).
__global__ __launch_bounds__(256) void gru_all(
        const float* __restrict__ z, const int* __restrict__ labels,
        const float* __restrict__ embed_w, const float* __restrict__ fc_w,
        const float* __restrict__ fc_b, const float* __restrict__ w_hh,
        const float* __restrict__ b_ih, const float* __restrict__ b_hh,
        const float* __restrict__ out_w, const float* __restrict__ out_b,
        float* __restrict__ out) {
    __shared__ __align__(16) __bf16 hbuf[2][MT * SB];  // [buf] bf16(h)
    __shared__ __align__(16) float  xs[MT * XSP];      // h0 input [z|embed]

    const int t = threadIdx.x;
    const int w = t >> 6;          // wave 0..3
    const int l = t & 63;
    const int q = l >> 4;          // quad 0..3
    const int n16 = l & 15;
    const int jg = 16 * w + n16;   // gate column this lane owns
    const int bbase = blockIdx.x * MT;

    // ---- prologue A: stage x = [z, embed(labels)] for 16 rows into LDS ----
    for (int c = t; c < MT * 24; c += 256) {    // 24 f32x4 chunks per row
        int m = c / 24, kk = (c % 24) * 4;
        f32x4 v;
        if (kk < 32) v = *(const f32x4*)(z + (size_t)(bbase + m) * 32 + kk);
        else         v = *(const f32x4*)(embed_w + labels[bbase + m] * 64 + (kk - 32));
        *(f32x4*)(xs + m * XSP + kk) = v;
    }

    // ---- persistent w_hh fragments (hi/lo split -> w is fp32-exact) ----
    // B-frag for mfma_f32_16x16x32_bf16: B[k = q*8+j][n16]; value w_hh[jg_g][k]
    bf16x8 whi[3][2], wlo[3][2];
#pragma unroll
    for (int g = 0; g < 3; ++g) {
        const float* pr = w_hh + (g * 64 + jg) * HDIM;
#pragma unroll
        for (int ks = 0; ks < 2; ++ks) {
            const float* p = pr + ks * 32 + q * 8;
            f32x4 va = *(const f32x4*)(p);
            f32x4 vb = *(const f32x4*)(p + 4);
#pragma unroll
            for (int j2 = 0; j2 < 4; ++j2) {
                __bf16 hiA = (__bf16)va[j2];
                whi[g][ks][j2] = hiA;
                wlo[g][ks][j2] = (__bf16)(va[j2] - (float)hiA);
                __bf16 hiB = (__bf16)vb[j2];
                whi[g][ks][4 + j2] = hiB;
                wlo[g][ks][4 + j2] = (__bf16)(vb[j2] - (float)hiB);
            }
        }
    }

    // ---- output-head B fragments: B[k][n] = out_w[n][k] for n<2 else 0 ----
    bf16x8 obhi[2], oblo[2];
#pragma unroll
    for (int ks = 0; ks < 2; ++ks) {
        f32x4 va = {0.f, 0.f, 0.f, 0.f}, vb = {0.f, 0.f, 0.f, 0.f};
        if (n16 < 2) {
            va = *(const f32x4*)(out_w + n16 * 64 + ks * 32 + q * 8);
            vb = *(const f32x4*)(out_w + n16 * 64 + ks * 32 + q * 8 + 4);
        }
#pragma unroll
        for (int j2 = 0; j2 < 4; ++j2) {
            __bf16 hiA = (__bf16)va[j2];
            obhi[ks][j2] = hiA;
            oblo[ks][j2] = (__bf16)(va[j2] - (float)hiA);
            __bf16 hiB = (__bf16)vb[j2];
            obhi[ks][4 + j2] = hiB;
            oblo[ks][4 + j2] = (__bf16)(vb[j2] - (float)hiB);
        }
    }
    const float bo = (n16 == 0) ? out_b[0] : (n16 == 1) ? out_b[1] : 0.f;
    const f32x4 obias = {bo, bo, bo, bo};
    const f32x4 kZ = {0.f, 0.f, 0.f, 0.f};

    // per-lane gate constants (biases folded into the exp2 fma)
    const float cR    = -L2E * (b_ih[jg] + b_hh[jg]);
    const float cZ    = -L2E * (b_ih[64 + jg] + b_hh[64 + jg]);
    const float bnacc = b_hh[128 + jg];
    const float cN    = 2.0f * L2E * b_ih[128 + jg];

    const int rdoff = n16 * SB + q * 8;    // A-frag element offset (16B-aligned)
    const int wroff = (4 * q) * SB + jg;   // state-write element offset
    float* oph = out + (size_t)(bbase + 4 * q) * (SEQ * 2) + n16;

    __syncthreads();   // xs ready

    // ---- prologue B: h0 = tanh(fc_b + fc_w . x); each lane -> its 4 rows ----
    float hprev[4];
    {
        float a[4];
#pragma unroll
        for (int r = 0; r < 4; ++r) a[r] = fc_b[jg];
        const float* wr = fc_w + jg * 96;
        for (int kc = 0; kc < 24; ++kc) {
            f32x4 wv = *(const f32x4*)(wr + kc * 4);
#pragma unroll
            for (int r = 0; r < 4; ++r) {
                f32x4 xv = *(const f32x4*)(xs + (4 * q + r) * XSP + kc * 4);
                a[r] += wv[0] * xv[0] + wv[1] * xv[1] + wv[2] * xv[2] + wv[3] * xv[3];
            }
        }
#pragma unroll
        for (int r = 0; r < 4; ++r) {
            float h = tanh_f(a[r]);
            hprev[r] = h;
            hbuf[0][wroff + r * SB] = (__bf16)h;
        }
    }
    __syncthreads();   // state 0 published in buf 0

    for (int u = 0; u < SEQ / 4; ++u) {
#pragma unroll
        for (int s = 0; s < 4; ++s) {
            const int p = s & 1;
            const __bf16* Hh = hbuf[p];
            __bf16* Nh = hbuf[1 - p];

            // A-frags of state i = 4u+s: A[m=n16][k=q*8+j], two k-halves
            bf16x8 ahi0 = *(const bf16x8*)(Hh + rdoff);
            bf16x8 ahi1 = *(const bf16x8*)(Hh + rdoff + 32);

            // output row i-1 (state i) on static duty wave (s+3)&3
            if ((u | s) != 0 && w == ((s + 3) & 3)) {
                f32x4 o = obias;
                o = MFMA(ahi0, obhi[0], o, 0, 0, 0);
                o = MFMA(ahi1, obhi[1], o, 0, 0, 0);
                o = MFMA(ahi0, oblo[0], o, 0, 0, 0);
                o = MFMA(ahi1, oblo[1], o, 0, 0, 0);
                if (n16 < 2) {
#pragma unroll
                    for (int r = 0; r < 4; ++r)
                        oph[r * (SEQ * 2) + 2 * s - 2] = o[r];
                }
            }

            // gates: 4-deep chain per gate (h_bf16 x [whi + wlo])
            f32x4 aR, aZ, aN;
            aR = MFMA(ahi0, whi[0][0], kZ, 0, 0, 0);
            aZ = MFMA(ahi0, whi[1][0], kZ, 0, 0, 0);
            aN = MFMA(ahi0, whi[2][0], kZ, 0, 0, 0);
            aR = MFMA(ahi1, whi[0][1], aR, 0, 0, 0);
            aZ = MFMA(ahi1, whi[1][1], aZ, 0, 0, 0);
            aN = MFMA(ahi1, whi[2][1], aN, 0, 0, 0);
            aR = MFMA(ahi0, wlo[0][0], aR, 0, 0, 0);
            aZ = MFMA(ahi0, wlo[1][0], aZ, 0, 0, 0);
            aN = MFMA(ahi0, wlo[2][0], aN, 0, 0, 0);
            aR = MFMA(ahi1, wlo[0][1], aR, 0, 0, 0);
            aZ = MFMA(ahi1, wlo[1][1], aZ, 0, 0, 0);
            aN = MFMA(ahi1, wlo[2][1], aN, 0, 0, 0);

#pragma unroll
            for (int r = 0; r < 4; ++r) {
                float eR = __builtin_amdgcn_exp2f(__builtin_fmaf(-L2E, aR[r], cR));
                float rg = __builtin_amdgcn_rcpf(eR + 1.0f);
                float eZ = __builtin_amdgcn_exp2f(__builtin_fmaf(-L2E, aZ[r], cZ));
                float zg = __builtin_amdgcn_rcpf(eZ + 1.0f);
                float m  = aN[r] + bnacc;
                float eN = __builtin_amdgcn_exp2f(__builtin_fmaf(2.0f * L2E, rg * m, cN));
                float d  = __builtin_amdgcn_rcpf(eN + 1.0f);
                float ng = __builtin_fmaf(-2.0f, d, 1.0f);
                float hn = __builtin_fmaf(zg, hprev[r] - ng, ng);  // exact fp32 carry
                hprev[r] = hn;
                Nh[wroff + r * SB] = (__bf16)hn;
            }
            __syncthreads();   // state i+1 published
        }
        oph += 8;   // 4 steps x 2 output cols
    }

    // final output: row 179 (state 180, in buf 0), duty wave 3
    if (w == 3) {
        const __bf16* Hh = hbuf[0];
        bf16x8 ahi0 = *(const bf16x8*)(Hh + rdoff);
        bf16x8 ahi1 = *(const bf16x8*)(Hh + rdoff + 32);
        f32x4 o = obias;
        o = MFMA(ahi0, obhi[0], o, 0, 0, 0);
        o = MFMA(ahi1, obhi[1], o, 0, 0, 0);
        o = MFMA(ahi0, oblo[0], o, 0, 0, 0);
        o = MFMA(ahi1, oblo[1], o, 0, 0, 0);
        if (n16 < 2) {
#pragma unroll
            for (int r = 0; r < 4; ++r)
                oph[r * (SEQ * 2) - 2] = o[r];
        }
    }
}

extern "C" void kernel_launch(void* const* d_in, const int* in_sizes, int n_in,
                              void* d_out, int out_size, void* d_ws, size_t ws_size,
                              hipStream_t stream) {
    (void)in_sizes; (void)n_in; (void)out_size; (void)d_ws; (void)ws_size;
    const float* z       = (const float*)d_in[0];
    const int*   labels  = (const int*)d_in[1];
    const float* embed_w = (const float*)d_in[2];
    const float* fc_w    = (const float*)d_in[3];
    const float* fc_b    = (const float*)d_in[4];
    // d_in[5] = w_ih: unused (GRU input is all zeros; b_ih carries the effect)
    const float* w_hh    = (const float*)d_in[6];
    const float* b_ih    = (const float*)d_in[7];
    const float* b_hh    = (const float*)d_in[8];
    const float* out_w   = (const float*)d_in[9];
    const float* out_b   = (const float*)d_in[10];
    float* out = (float*)d_out;

    gru_all<<<NB / MT, 256, 0, stream>>>(z, labels, embed_w, fc_w, fc_b,
                                         w_hh, b_ih, b_hh, out_w, out_b, out);
}